// Round 18
// baseline (115.621 us; speedup 1.0000x reference)
//
#include <hip/hip_runtime.h>
#include <stdint.h>

#define Bn 2048
#define Dn 1024
#define Hn 2048
#define On 512
#define En 8

typedef float f32x4 __attribute__((ext_vector_type(4)));
typedef unsigned short ushort_t;
typedef unsigned char u8;

__device__ __forceinline__ void gload16(const void* g, void* l) {
  __builtin_amdgcn_global_load_lds((const uint32_t*)g, (uint32_t*)l, 16, 0, 0);
}

// pack 4 floats -> 4 fp8 e4m3 in one dword
__device__ __forceinline__ int pk4_fp8(float a, float b, float c, float d) {
  int w = __builtin_amdgcn_cvt_pk_fp8_f32(a, b, 0, false);
  w = __builtin_amdgcn_cvt_pk_fp8_f32(c, d, w, true);
  return w;
}

__device__ __forceinline__ u8 f2fp8(float v) {
  int w = __builtin_amdgcn_cvt_pk_fp8_f32(v, v, 0, false);
  return (u8)(w & 0xff);
}

// ---------------- init: zero counts/cursors every launch (determinism) ----------------
__global__ void init_kernel(int* counts, int* cursors) {
  int t = threadIdx.x;
  if (t < En) { counts[t] = 0; cursors[t] = 0; }
}

// == fused prep: gating | tcast fc1_w->fp8 | tcast fc2_w->fp8 | x->fp8 (range-dispatch) ==
#define NB_G (Bn / 8)
#define NB_T1 ((Dn / 256) * (Hn / 64) * En)   // 4*32*8 = 1024
#define NB_T2 ((Hn / 256) * (On / 64) * En)   // 8*8*8  = 512
#define NB_X (Bn * Dn / 4096)                 // 512
#define WSCALE 64.0f

// 256(r) x 64(c) transpose tile -> fp8 (x WSCALE). fp8 LDS [c=64][r=256, stride 272].
// Read: thread packs 4 rows x 4 cols -> 4 LDS dword writes (2-way bank, free).
// Write: 4 output rows/wave, 256 B contiguous each (int4 x4 per thread).
__device__ __forceinline__ void tcast_f8_256(const float* __restrict__ inp,
                                             u8* __restrict__ outp,
                                             int R, int C, int r0, int c0, u8* lds) {
  int t = threadIdx.x;
  int cc4 = (t & 15) * 4;   // col base 0..60
  int rr4 = (t >> 4) * 4;   // row-in-pass base 0..60
#pragma unroll
  for (int pass = 0; pass < 4; pass++) {
    int rbase = pass * 64 + rr4;  // 0..252
    uint32_t wds[4] = {0, 0, 0, 0};
#pragma unroll
    for (int i = 0; i < 4; i++) {
      float4 v = *(const float4*)&inp[(size_t)(r0 + rbase + i) * C + c0 + cc4];
      wds[0] |= (uint32_t)f2fp8(v.x * WSCALE) << (8 * i);
      wds[1] |= (uint32_t)f2fp8(v.y * WSCALE) << (8 * i);
      wds[2] |= (uint32_t)f2fp8(v.z * WSCALE) << (8 * i);
      wds[3] |= (uint32_t)f2fp8(v.w * WSCALE) << (8 * i);
    }
#pragma unroll
    for (int j = 0; j < 4; j++)
      *(uint32_t*)&lds[(cc4 + j) * 272 + rbase] = wds[j];
  }
  __syncthreads();
  int j = t >> 2, q = t & 3;  // output row j (0..63), 64B chunk q
  const u8* lp = &lds[j * 272 + q * 64];
  int4 d0 = *(const int4*)(lp);
  int4 d1 = *(const int4*)(lp + 16);
  int4 d2 = *(const int4*)(lp + 32);
  int4 d3 = *(const int4*)(lp + 48);
  u8* op = &outp[(size_t)(c0 + j) * R + r0 + q * 64];
  *(int4*)(op) = d0;
  *(int4*)(op + 16) = d1;
  *(int4*)(op + 32) = d2;
  *(int4*)(op + 48) = d3;
}

__global__ __launch_bounds__(256) void prep_kernel(
    const float* __restrict__ x, const float* __restrict__ wg,
    const float* __restrict__ fc1w, const float* __restrict__ fc2w,
    u8* __restrict__ x_f8, u8* __restrict__ w1t8, u8* __restrict__ w2t8,
    int* __restrict__ top_idx, float* __restrict__ gates, int* __restrict__ counts) {
  __shared__ float smem[En * Dn];  // 32 KB (gating f32 / transpose fp8 tile)
  __shared__ int lcnt[En];
  int bid = blockIdx.x;
  int t = threadIdx.x;

  if (bid < NB_G) {
    // ---- gating: 8 rows/block ----
    float* wgs = smem;
    for (int i = t; i < Dn * En; i += 256) {
      int d = i >> 3, e = i & 7;
      wgs[e * Dn + d] = wg[i];  // wg is [d][e]
    }
    if (t < En) lcnt[t] = 0;
    __syncthreads();
    int w = t >> 6, lane = t & 63;
#pragma unroll
    for (int r = 0; r < 2; r++) {
      int b = bid * 8 + w * 2 + r;
      const float* xr = x + (size_t)b * Dn;
      float xv[16];
#pragma unroll
      for (int j = 0; j < 16; j++) xv[j] = xr[lane + j * 64];
      float acc[En];
#pragma unroll
      for (int e = 0; e < En; e++) acc[e] = 0.f;
#pragma unroll
      for (int j = 0; j < 16; j++) {
        int d = lane + j * 64;
#pragma unroll
        for (int e = 0; e < En; e++) acc[e] += xv[j] * wgs[e * Dn + d];
      }
#pragma unroll
      for (int off = 32; off; off >>= 1) {
#pragma unroll
        for (int e = 0; e < En; e++) acc[e] += __shfl_down(acc[e], off);
      }
      if (lane == 0) {
        float best = -1e30f, second = -1e30f; int bi = 0, si = 0;
#pragma unroll
        for (int e = 0; e < En; e++) {
          float l = acc[e];
          if (l > best) { second = best; si = bi; best = l; bi = e; }
          else if (l > second) { second = l; si = e; }
        }
        float e1 = expf(second - best);
        float inv = 1.f / (1.f + e1);
        top_idx[2 * b] = bi; top_idx[2 * b + 1] = si;
        gates[2 * b] = inv;  gates[2 * b + 1] = e1 * inv;
        atomicAdd(&lcnt[bi], 1);
        atomicAdd(&lcnt[si], 1);
      }
    }
    __syncthreads();
    if (t < En) {
      int c = lcnt[t];
      if (c) atomicAdd(&counts[t], c);
    }
  } else if (bid < NB_G + NB_T1) {
    // ---- fc1_w [E][Dn][Hn] -> w1t8 [E][Hn][Dn] fp8 ----
    int idx = bid - NB_G;
    constexpr int TPE = (Dn / 256) * (Hn / 64);
    int z = idx / TPE, rem = idx % TPE;
    int r0 = (rem / (Hn / 64)) * 256, c0 = (rem % (Hn / 64)) * 64;
    tcast_f8_256(fc1w + (size_t)z * Dn * Hn, w1t8 + (size_t)z * Dn * Hn, Dn, Hn, r0, c0,
                 (u8*)smem);
  } else if (bid < NB_G + NB_T1 + NB_T2) {
    // ---- fc2_w [E][Hn][On] -> w2t8 [E][On][Hn] fp8 ----
    int idx = bid - NB_G - NB_T1;
    constexpr int TPE = (Hn / 256) * (On / 64);
    int z = idx / TPE, rem = idx % TPE;
    int r0 = (rem / (On / 64)) * 256, c0 = (rem % (On / 64)) * 64;
    tcast_f8_256(fc2w + (size_t)z * Hn * On, w2t8 + (size_t)z * Hn * On, Hn, On, r0, c0,
                 (u8*)smem);
  } else {
    // ---- x f32 -> fp8, 16 contiguous elems per thread ----
    int i = (bid - NB_G - NB_T1 - NB_T2) * 256 + t;
    const float4* p = (const float4*)x + (size_t)i * 4;
    float4 a = p[0], b = p[1], c = p[2], d = p[3];
    int4 o;
    o.x = pk4_fp8(a.x, a.y, a.z, a.w);
    o.y = pk4_fp8(b.x, b.y, b.z, b.w);
    o.z = pk4_fp8(c.x, c.y, c.z, c.w);
    o.w = pk4_fp8(d.x, d.y, d.z, d.w);
    *(int4*)(x_f8 + (size_t)i * 16) = o;
  }
}

// ---------------- offsets (exclusive prefix over 8 counts) ----------------
__global__ void offsets_kernel(const int* counts, int* offsets, int* cursors) {
  if (threadIdx.x == 0) {
    int s = 0;
    for (int e = 0; e < En; e++) { offsets[e] = s; s += counts[e]; }
  }
  if (threadIdx.x < En) cursors[threadIdx.x] = 0;
}

// ---------------- assign rows to compact slots ----------------
__global__ void assign_kernel(const int* __restrict__ top_idx, const int* __restrict__ offsets,
                              int* cursors, int* __restrict__ s2r, int* __restrict__ r2s) {
  int b = blockIdx.x * 256 + threadIdx.x;
  if (b >= Bn) return;
#pragma unroll
  for (int k = 0; k < 2; k++) {
    int e = top_idx[2 * b + k];
    int pos = atomicAdd(&cursors[e], 1);
    int slot = offsets[e] + pos;
    s2r[slot] = b;
    r2s[2 * b + k] = slot;
  }
}

// ---- fp8 grouped GEMM: 64x64 x 64B-K-step, 4 waves (2Mx2N), mfma_f32_16x16x32_fp8_fp8 ----
// r16/r17-proven structure. W pre-scaled x64 -> epilogue unscales 1/64 before bias.
template <bool FC1, int N, int K, int SPLITK>
__global__ __launch_bounds__(256, 8) void fp8_gemm_kernel(
    const u8* __restrict__ A, const u8* __restrict__ WT,
    const float* __restrict__ bias, const int* __restrict__ offsets,
    const int* __restrict__ counts, const int* __restrict__ s2r,
    u8* __restrict__ outH8, float* __restrict__ outL, float* __restrict__ outL2) {
  constexpr int NBL = N / 64;
  constexpr int KS = K / SPLITK;
  constexpr int NT = KS / 64;
  int e = blockIdx.z;
  int cnt = counts[e];
  int rb = blockIdx.y;
  if (rb * 64 >= cnt) return;
  int base = offsets[e];
  int ks = blockIdx.x / NBL;
  int nb = (blockIdx.x % NBL) * 64;
  int k0 = ks * KS;
  __shared__ __align__(16) u8 As[64 * 64];  // 4 KB
  __shared__ __align__(16) u8 Bs[64 * 64];  // 4 KB
  int t = threadIdx.x;
  int lane = t & 63, w = t >> 6;
  int wr = w >> 1, wc = w & 1;

  int srow = t >> 2;                           // 0..63 staging row
  int sslot = (t & 3) ^ ((srow >> 1) & 3);     // pre-swizzled global 16B slot
  int scol = sslot * 16;

  int lr = rb * 64 + srow;
  int lrc = lr < cnt ? lr : cnt - 1;
  const u8* aptr = A + (size_t)(FC1 ? s2r[base + lrc] : (base + lrc)) * K + k0 + scol;
  const u8* bptr = WT + ((size_t)e * N + nb + srow) * K + k0 + scol;

  f32x4 zero = {0.f, 0.f, 0.f, 0.f};
  f32x4 acc[2][2];
#pragma unroll
  for (int m = 0; m < 2; m++)
#pragma unroll
    for (int n = 0; n < 2; n++) acc[m][n] = zero;

  int a_r = wr * 32 + (lane & 15);       // A fragment row
  int b_r = wc * 32 + (lane & 15);       // B fragment row
  int rkey = ((lane & 15) >> 1) & 3;     // (row>>1)&3 (row bases mult of 16 -> invariant)
  int slb = (lane >> 4) >> 1;            // logical 16B-slot sub-index (0/1)
  int half = ((lane >> 4) & 1) * 8;      // 8B half within slot

  for (int kt = 0; kt < NT; kt++) {
    gload16(aptr + kt * 64, &As[t * 16]);   // linear dest: row t>>2, slot t&3
    gload16(bptr + kt * 64, &Bs[t * 16]);
    __syncthreads();  // drains vmcnt before LDS reads
#pragma unroll
    for (int kk = 0; kk < 2; kk++) {
      long af[2], bfr[2];
#pragma unroll
      for (int m = 0; m < 2; m++)
        af[m] = *(const long*)(As + (a_r + m * 16) * 64 +
                               (((kk * 2 + slb) ^ rkey) << 4) + half);
#pragma unroll
      for (int n = 0; n < 2; n++)
        bfr[n] = *(const long*)(Bs + (b_r + n * 16) * 64 +
                                (((kk * 2 + slb) ^ rkey) << 4) + half);
#pragma unroll
      for (int m = 0; m < 2; m++)
#pragma unroll
        for (int n = 0; n < 2; n++)
          acc[m][n] = __builtin_amdgcn_mfma_f32_16x16x32_fp8_fp8(af[m], bfr[n], acc[m][n], 0, 0, 0);
    }
    __syncthreads();  // protect LDS before next stage
  }

  // epilogue: D layout col=lane&15, row=(lane>>4)*4+i; unscale 1/64
  const float INV = 1.0f / WSCALE;
  float* dst = (SPLITK > 1 && ks > 0) ? outL2 : outL;
  int lr0 = rb * 64 + wr * 32;
#pragma unroll
  for (int m = 0; m < 2; m++) {
#pragma unroll
    for (int i = 0; i < 4; i++) {
      int orow = lr0 + m * 16 + (lane >> 4) * 4 + i;
      if (orow < cnt) {
        int slot = base + orow;
#pragma unroll
        for (int n = 0; n < 2; n++) {
          int col = nb + wc * 32 + n * 16 + (lane & 15);
          if (FC1) {
            float v = acc[m][n][i] * INV + bias[e * N + col];
            float g = 0.5f * v * (1.0f + erff(v * 0.70710678118654752f));
            outH8[(size_t)slot * N + col] = f2fp8(g);
          } else {
            float v = acc[m][n][i] * INV + (ks == 0 ? bias[e * N + col] : 0.f);
            dst[(size_t)slot * N + col] = v;
          }
        }
      }
    }
  }
}

// ---------------- combine: sum 2 split-K partials, logsoftmax over O=512, weighted sum ----------------
__device__ __forceinline__ float blk_reduce(float v, bool ismax) {
  __shared__ float sbuf[4];
  int lane = threadIdx.x & 63, w = threadIdx.x >> 6;
#pragma unroll
  for (int off = 32; off; off >>= 1) {
    float o = __shfl_down(v, off);
    v = ismax ? fmaxf(v, o) : (v + o);
  }
  __syncthreads();
  if (lane == 0) sbuf[w] = v;
  __syncthreads();
  float r = sbuf[0];
#pragma unroll
  for (int i = 1; i < 4; i++) r = ismax ? fmaxf(r, sbuf[i]) : (r + sbuf[i]);
  return r;
}

__global__ void combine_kernel(const float* __restrict__ l2a, const float* __restrict__ l2b,
                               const int* __restrict__ r2s, const float* __restrict__ gates,
                               float* __restrict__ out) {
  int b = blockIdx.x, t = threadIdx.x;
  float c0 = 0.f, c1 = 0.f;
#pragma unroll
  for (int k = 0; k < 2; k++) {
    int slot = r2s[2 * b + k];
    float g = gates[2 * b + k];
    const float* lp0 = l2a + (size_t)slot * On;
    const float* lp1 = l2b + (size_t)slot * On;
    float v0 = lp0[t] + lp1[t];
    float v1 = lp0[t + 256] + lp1[t + 256];
    float m = blk_reduce(fmaxf(v0, v1), true);
    float s = blk_reduce(expf(v0 - m) + expf(v1 - m), false);
    float lse = m + logf(s);
    c0 += g * expf(v0 - lse);
    c1 += g * expf(v1 - lse);
  }
  const float EPSv = 2.220446049250313e-16f;
  out[(size_t)b * On + t] = logf(fmaxf(c0, EPSv));
  out[(size_t)b * On + t + 256] = logf(fmaxf(c1, EPSv));
}

extern "C" void kernel_launch(void* const* d_in, const int* in_sizes, int n_in,
                              void* d_out, int out_size, void* d_ws, size_t ws_size,
                              hipStream_t stream) {
  const float* x = (const float*)d_in[0];
  const float* wgate = (const float*)d_in[1];
  const float* fc1w = (const float*)d_in[2];
  const float* fc1b = (const float*)d_in[3];
  const float* fc2w = (const float*)d_in[4];
  const float* fc2b = (const float*)d_in[5];
  float* out = (float*)d_out;

  char* ws = (char*)d_ws;
  size_t o = 0;
  u8* x_f8     = (u8*)(ws + o);    o += (size_t)Bn * Dn;          // 2 MB
  u8* w1t8     = (u8*)(ws + o);    o += (size_t)En * Hn * Dn;     // 16 MB [E][H][D] fp8
  u8* w2t8     = (u8*)(ws + o);    o += (size_t)En * On * Hn;     // 8 MB  [E][O][H] fp8
  u8* hbuf8    = (u8*)(ws + o);    o += (size_t)2 * Bn * Hn;      // 4 MB  [slot][H] fp8
  float* l2buf = (float*)(ws + o); o += (size_t)2 * Bn * On * 4;  // 8 MB partial 0
  int* top_idx = (int*)(ws + o);   o += (size_t)Bn * 2 * 4;
  float* gates = (float*)(ws + o); o += (size_t)Bn * 2 * 4;
  int* r2s     = (int*)(ws + o);   o += (size_t)Bn * 2 * 4;
  int* s2r     = (int*)(ws + o);   o += (size_t)2 * Bn * 4;
  int* counts  = (int*)(ws + o);   o += 64;
  int* offsets = (int*)(ws + o);   o += 64;
  int* cursors = (int*)(ws + o);   o += 64;
  // split-K partial 1 (8 MB) aliases w1t8 (16 MB): w1t8 is fully consumed by fc1
  // (completes before fc2 starts, same stream) and rewritten by prep each launch.
  float* l2buf1 = (float*)w1t8;

  hipLaunchKernelGGL(init_kernel, dim3(1), dim3(64), 0, stream, counts, cursors);
  hipLaunchKernelGGL(prep_kernel, dim3(NB_G + NB_T1 + NB_T2 + NB_X), dim3(256), 0, stream,
                     x, wgate, fc1w, fc2w, x_f8, w1t8, w2t8, top_idx, gates, counts);
  hipLaunchKernelGGL(offsets_kernel, dim3(1), dim3(64), 0, stream, counts, offsets, cursors);
  hipLaunchKernelGGL(assign_kernel, dim3(Bn / 256), dim3(256), 0, stream,
                     top_idx, offsets, cursors, s2r, r2s);
  hipLaunchKernelGGL((fp8_gemm_kernel<true, Hn, Dn, 1>), dim3(Hn / 64, 32, En), dim3(256),
                     0, stream, x_f8, w1t8, fc1b, offsets, counts, s2r, hbuf8,
                     (float*)nullptr, (float*)nullptr);
  hipLaunchKernelGGL((fp8_gemm_kernel<false, On, Hn, 2>), dim3((On / 64) * 2, 32, En), dim3(256),
                     0, stream, hbuf8, w2t8, fc2b, offsets, counts, s2r, (u8*)nullptr,
                     l2buf, l2buf1);
  hipLaunchKernelGGL(combine_kernel, dim3(Bn), dim3(256), 0, stream, l2buf, l2buf1, r2s, gates, out);
}

// Round 19
// 114.040 us; speedup vs baseline: 1.0139x; 1.0139x over previous
//
#include <hip/hip_runtime.h>
#include <stdint.h>

#define Bn 2048
#define Dn 1024
#define Hn 2048
#define On 512
#define En 8

typedef float f32x4 __attribute__((ext_vector_type(4)));
typedef unsigned char u8;

__device__ __forceinline__ void gload16(const void* g, void* l) {
  __builtin_amdgcn_global_load_lds((const uint32_t*)g, (uint32_t*)l, 16, 0, 0);
}

__device__ __forceinline__ u8 f2fp8(float v) {
  int w = __builtin_amdgcn_cvt_pk_fp8_f32(v, v, 0, false);
  return (u8)(w & 0xff);
}

// ---------------- init: zero counts/cursors every launch (determinism) ----------------
__global__ void init_kernel(int* counts, int* cursors) {
  int t = threadIdx.x;
  if (t < En) { counts[t] = 0; cursors[t] = 0; }
}

// == fused prep: gating+x->fp8 (512 blks) | tcast fc1_w->fp8 | tcast fc2_w->fp8 ==
#define NB_G (Bn / 4)
#define NB_T1 ((Dn / 256) * (Hn / 64) * En)   // 4*32*8 = 1024
#define NB_T2 ((Hn / 256) * (On / 64) * En)   // 8*8*8  = 512
#define WSCALE 64.0f

// 256(r) x 64(c) transpose tile -> fp8 (x WSCALE).
// LDS: column-major dwords, column stride 65 dw (260 B) -> write bank = 4k mod 32
// (~2-way, free); read bank = c+16q+i (2-way). Output: 256 B contiguous per row.
__device__ __forceinline__ void tcast_f8_256(const float* __restrict__ inp,
                                             u8* __restrict__ outp,
                                             int R, int C, int r0, int c0, uint32_t* L) {
  int t = threadIdx.x;
  int cc4 = (t & 15) * 4;   // col base 0..60
  int rg = t >> 4;          // 0..15
#pragma unroll
  for (int p = 0; p < 4; p++) {
    int rbase = p * 64 + rg * 4;
    uint32_t wds[4] = {0, 0, 0, 0};
#pragma unroll
    for (int i = 0; i < 4; i++) {
      float4 v = *(const float4*)&inp[(size_t)(r0 + rbase + i) * C + c0 + cc4];
      wds[0] |= (uint32_t)f2fp8(v.x * WSCALE) << (8 * i);
      wds[1] |= (uint32_t)f2fp8(v.y * WSCALE) << (8 * i);
      wds[2] |= (uint32_t)f2fp8(v.z * WSCALE) << (8 * i);
      wds[3] |= (uint32_t)f2fp8(v.w * WSCALE) << (8 * i);
    }
    int rd = p * 16 + rg;
#pragma unroll
    for (int j = 0; j < 4; j++) L[(cc4 + j) * 65 + rd] = wds[j];
  }
  __syncthreads();
  int c = t >> 2, q = t & 3;  // output row c (0..63), 64B chunk q
  uint32_t dw[16];
#pragma unroll
  for (int i = 0; i < 16; i++) dw[i] = L[c * 65 + q * 16 + i];
  u8* op = &outp[(size_t)(c0 + c) * R + r0 + q * 64];
#pragma unroll
  for (int s = 0; s < 4; s++) {
    int4 o = make_int4((int)dw[4 * s], (int)dw[4 * s + 1], (int)dw[4 * s + 2],
                       (int)dw[4 * s + 3]);
    *(int4*)(op + 16 * s) = o;
  }
}

__global__ __launch_bounds__(256) void prep_kernel(
    const float* __restrict__ x, const float* __restrict__ wg,
    const float* __restrict__ fc1w, const float* __restrict__ fc2w,
    u8* __restrict__ x_f8, u8* __restrict__ w1t8, u8* __restrict__ w2t8,
    int* __restrict__ top_idx, float* __restrict__ gates, int* __restrict__ counts) {
  __shared__ __align__(16) float smem[En * Dn];  // 32 KB (gating wg / transpose dwords)
  __shared__ int lcnt[En];
  int bid = blockIdx.x;
  int t = threadIdx.x;

  if (bid < NB_G) {
    // ---- gating + x->fp8: 4 rows/block, wave w -> row bid*4+w ----
    float* wgs = smem;
    for (int i = t; i < Dn * En; i += 256) {
      int d = i >> 3, e = i & 7;
      wgs[e * Dn + d] = wg[i];  // wg is [d][e]
    }
    if (t < En) lcnt[t] = 0;
    __syncthreads();
    int w = t >> 6, lane = t & 63;
    int b = bid * 4 + w;
    const float* xr = x + (size_t)b * Dn;
    u8* xo = x_f8 + (size_t)b * Dn;
    float xv[16];
#pragma unroll
    for (int j = 0; j < 16; j++) xv[j] = xr[lane + j * 64];
    float acc[En];
#pragma unroll
    for (int e = 0; e < En; e++) acc[e] = 0.f;
#pragma unroll
    for (int j = 0; j < 16; j++) {
      int d = lane + j * 64;
      xo[d] = f2fp8(xv[j]);  // byte store, lane-coalesced (64 B/wave)
#pragma unroll
      for (int e = 0; e < En; e++) acc[e] += xv[j] * wgs[e * Dn + d];
    }
#pragma unroll
    for (int off = 32; off; off >>= 1) {
#pragma unroll
      for (int e = 0; e < En; e++) acc[e] += __shfl_down(acc[e], off);
    }
    if (lane == 0) {
      float best = -1e30f, second = -1e30f; int bi = 0, si = 0;
#pragma unroll
      for (int e = 0; e < En; e++) {
        float l = acc[e];
        if (l > best) { second = best; si = bi; best = l; bi = e; }
        else if (l > second) { second = l; si = e; }
      }
      float e1 = expf(second - best);
      float inv = 1.f / (1.f + e1);
      top_idx[2 * b] = bi; top_idx[2 * b + 1] = si;
      gates[2 * b] = inv;  gates[2 * b + 1] = e1 * inv;
      atomicAdd(&lcnt[bi], 1);
      atomicAdd(&lcnt[si], 1);
    }
    __syncthreads();
    if (t < En) {
      int c = lcnt[t];
      if (c) atomicAdd(&counts[t], c);
    }
  } else if (bid < NB_G + NB_T1) {
    // ---- fc1_w [E][Dn][Hn] -> w1t8 [E][Hn][Dn] fp8 ----
    int idx = bid - NB_G;
    constexpr int TPE = (Dn / 256) * (Hn / 64);
    int z = idx / TPE, rem = idx % TPE;
    int r0 = (rem / (Hn / 64)) * 256, c0 = (rem % (Hn / 64)) * 64;
    tcast_f8_256(fc1w + (size_t)z * Dn * Hn, w1t8 + (size_t)z * Dn * Hn, Dn, Hn, r0, c0,
                 (uint32_t*)smem);
  } else {
    // ---- fc2_w [E][Hn][On] -> w2t8 [E][On][Hn] fp8 ----
    int idx = bid - NB_G - NB_T1;
    constexpr int TPE = (Hn / 256) * (On / 64);
    int z = idx / TPE, rem = idx % TPE;
    int r0 = (rem / (On / 64)) * 256, c0 = (rem % (On / 64)) * 64;
    tcast_f8_256(fc2w + (size_t)z * Hn * On, w2t8 + (size_t)z * Hn * On, Hn, On, r0, c0,
                 (uint32_t*)smem);
  }
}

// -------- assign rows to compact slots (offsets computed inline from counts) --------
__global__ void assign_kernel(const int* __restrict__ top_idx, const int* __restrict__ counts,
                              int* cursors, int* __restrict__ s2r, int* __restrict__ r2s) {
  int b = blockIdx.x * 256 + threadIdx.x;
  if (b >= Bn) return;
  int offs[En];
  int s = 0;
#pragma unroll
  for (int e = 0; e < En; e++) { offs[e] = s; s += counts[e]; }
#pragma unroll
  for (int k = 0; k < 2; k++) {
    int e = top_idx[2 * b + k];
    int pos = atomicAdd(&cursors[e], 1);
    int slot = offs[e] + pos;
    s2r[slot] = b;
    r2s[2 * b + k] = slot;
  }
}

// ---- fp8 grouped GEMM: 64x64 x 64B-K-step, 4 waves (2Mx2N), mfma_f32_16x16x32_fp8_fp8 ----
// r16/r17-proven structure. W pre-scaled x64 -> epilogue unscales 1/64 before bias.
template <bool FC1, int N, int K, int SPLITK>
__global__ __launch_bounds__(256, 8) void fp8_gemm_kernel(
    const u8* __restrict__ A, const u8* __restrict__ WT,
    const float* __restrict__ bias, const int* __restrict__ counts,
    const int* __restrict__ s2r,
    u8* __restrict__ outH8, float* __restrict__ outL, float* __restrict__ outL2) {
  constexpr int NBL = N / 64;
  constexpr int KS = K / SPLITK;
  constexpr int NT = KS / 64;
  int e = blockIdx.z;
  int cnt = counts[e];
  int rb = blockIdx.y;
  if (rb * 64 >= cnt) return;
  int base = 0;
#pragma unroll
  for (int i = 0; i < En; i++) base += (i < e) ? counts[i] : 0;
  int ks = blockIdx.x / NBL;
  int nb = (blockIdx.x % NBL) * 64;
  int k0 = ks * KS;
  __shared__ __align__(16) u8 As[64 * 64];  // 4 KB
  __shared__ __align__(16) u8 Bs[64 * 64];  // 4 KB
  int t = threadIdx.x;
  int lane = t & 63, w = t >> 6;
  int wr = w >> 1, wc = w & 1;

  int srow = t >> 2;                           // 0..63 staging row
  int sslot = (t & 3) ^ ((srow >> 1) & 3);     // pre-swizzled global 16B slot
  int scol = sslot * 16;

  int lr = rb * 64 + srow;
  int lrc = lr < cnt ? lr : cnt - 1;
  const u8* aptr = A + (size_t)(FC1 ? s2r[base + lrc] : (base + lrc)) * K + k0 + scol;
  const u8* bptr = WT + ((size_t)e * N + nb + srow) * K + k0 + scol;

  f32x4 zero = {0.f, 0.f, 0.f, 0.f};
  f32x4 acc[2][2];
#pragma unroll
  for (int m = 0; m < 2; m++)
#pragma unroll
    for (int n = 0; n < 2; n++) acc[m][n] = zero;

  int a_r = wr * 32 + (lane & 15);       // A fragment row
  int b_r = wc * 32 + (lane & 15);       // B fragment row
  int rkey = ((lane & 15) >> 1) & 3;     // (row>>1)&3 (row bases mult of 16 -> invariant)
  int slb = (lane >> 4) >> 1;            // logical 16B-slot sub-index (0/1)
  int half = ((lane >> 4) & 1) * 8;      // 8B half within slot

  for (int kt = 0; kt < NT; kt++) {
    gload16(aptr + kt * 64, &As[t * 16]);   // linear dest: row t>>2, slot t&3
    gload16(bptr + kt * 64, &Bs[t * 16]);
    __syncthreads();  // drains vmcnt before LDS reads
#pragma unroll
    for (int kk = 0; kk < 2; kk++) {
      long af[2], bfr[2];
#pragma unroll
      for (int m = 0; m < 2; m++)
        af[m] = *(const long*)(As + (a_r + m * 16) * 64 +
                               (((kk * 2 + slb) ^ rkey) << 4) + half);
#pragma unroll
      for (int n = 0; n < 2; n++)
        bfr[n] = *(const long*)(Bs + (b_r + n * 16) * 64 +
                                (((kk * 2 + slb) ^ rkey) << 4) + half);
#pragma unroll
      for (int m = 0; m < 2; m++)
#pragma unroll
        for (int n = 0; n < 2; n++)
          acc[m][n] = __builtin_amdgcn_mfma_f32_16x16x32_fp8_fp8(af[m], bfr[n], acc[m][n], 0, 0, 0);
    }
    __syncthreads();  // protect LDS before next stage
  }

  // epilogue: D layout col=lane&15, row=(lane>>4)*4+i; unscale 1/64
  const float INV = 1.0f / WSCALE;
  float* dst = (SPLITK > 1 && ks > 0) ? outL2 : outL;
  int lr0 = rb * 64 + wr * 32;
#pragma unroll
  for (int m = 0; m < 2; m++) {
#pragma unroll
    for (int i = 0; i < 4; i++) {
      int orow = lr0 + m * 16 + (lane >> 4) * 4 + i;
      if (orow < cnt) {
        int slot = base + orow;
#pragma unroll
        for (int n = 0; n < 2; n++) {
          int col = nb + wc * 32 + n * 16 + (lane & 15);
          if (FC1) {
            float v = acc[m][n][i] * INV + bias[e * N + col];
            float g = 0.5f * v * (1.0f + erff(v * 0.70710678118654752f));
            outH8[(size_t)slot * N + col] = f2fp8(g);
          } else {
            float v = acc[m][n][i] * INV + (ks == 0 ? bias[e * N + col] : 0.f);
            dst[(size_t)slot * N + col] = v;
          }
        }
      }
    }
  }
}

// ---------------- combine: sum 2 split-K partials, logsoftmax over O=512, weighted sum ----------------
__device__ __forceinline__ float blk_reduce(float v, bool ismax) {
  __shared__ float sbuf[4];
  int lane = threadIdx.x & 63, w = threadIdx.x >> 6;
#pragma unroll
  for (int off = 32; off; off >>= 1) {
    float o = __shfl_down(v, off);
    v = ismax ? fmaxf(v, o) : (v + o);
  }
  __syncthreads();
  if (lane == 0) sbuf[w] = v;
  __syncthreads();
  float r = sbuf[0];
#pragma unroll
  for (int i = 1; i < 4; i++) r = ismax ? fmaxf(r, sbuf[i]) : (r + sbuf[i]);
  return r;
}

__global__ void combine_kernel(const float* __restrict__ l2a, const float* __restrict__ l2b,
                               const int* __restrict__ r2s, const float* __restrict__ gates,
                               float* __restrict__ out) {
  int b = blockIdx.x, t = threadIdx.x;
  float c0 = 0.f, c1 = 0.f;
#pragma unroll
  for (int k = 0; k < 2; k++) {
    int slot = r2s[2 * b + k];
    float g = gates[2 * b + k];
    const float* lp0 = l2a + (size_t)slot * On;
    const float* lp1 = l2b + (size_t)slot * On;
    float v0 = lp0[t] + lp1[t];
    float v1 = lp0[t + 256] + lp1[t + 256];
    float m = blk_reduce(fmaxf(v0, v1), true);
    float s = blk_reduce(expf(v0 - m) + expf(v1 - m), false);
    float lse = m + logf(s);
    c0 += g * expf(v0 - lse);
    c1 += g * expf(v1 - lse);
  }
  const float EPSv = 2.220446049250313e-16f;
  out[(size_t)b * On + t] = logf(fmaxf(c0, EPSv));
  out[(size_t)b * On + t + 256] = logf(fmaxf(c1, EPSv));
}

extern "C" void kernel_launch(void* const* d_in, const int* in_sizes, int n_in,
                              void* d_out, int out_size, void* d_ws, size_t ws_size,
                              hipStream_t stream) {
  const float* x = (const float*)d_in[0];
  const float* wgate = (const float*)d_in[1];
  const float* fc1w = (const float*)d_in[2];
  const float* fc1b = (const float*)d_in[3];
  const float* fc2w = (const float*)d_in[4];
  const float* fc2b = (const float*)d_in[5];
  float* out = (float*)d_out;

  char* ws = (char*)d_ws;
  size_t o = 0;
  u8* x_f8     = (u8*)(ws + o);    o += (size_t)Bn * Dn;          // 2 MB
  u8* w1t8     = (u8*)(ws + o);    o += (size_t)En * Hn * Dn;     // 16 MB [E][H][D] fp8
  u8* w2t8     = (u8*)(ws + o);    o += (size_t)En * On * Hn;     // 8 MB  [E][O][H] fp8
  u8* hbuf8    = (u8*)(ws + o);    o += (size_t)2 * Bn * Hn;      // 4 MB  [slot][H] fp8
  float* l2buf = (float*)(ws + o); o += (size_t)2 * Bn * On * 4;  // 8 MB partial 0
  int* top_idx = (int*)(ws + o);   o += (size_t)Bn * 2 * 4;
  float* gates = (float*)(ws + o); o += (size_t)Bn * 2 * 4;
  int* r2s     = (int*)(ws + o);   o += (size_t)Bn * 2 * 4;
  int* s2r     = (int*)(ws + o);   o += (size_t)2 * Bn * 4;
  int* counts  = (int*)(ws + o);   o += 64;
  int* cursors = (int*)(ws + o);   o += 64;
  // split-K partial 1 (8 MB) aliases w1t8 (16 MB): w1t8 is fully consumed by fc1
  // (completes before fc2 starts, same stream) and rewritten by prep each launch.
  float* l2buf1 = (float*)w1t8;

  hipLaunchKernelGGL(init_kernel, dim3(1), dim3(64), 0, stream, counts, cursors);
  hipLaunchKernelGGL(prep_kernel, dim3(NB_G + NB_T1 + NB_T2), dim3(256), 0, stream,
                     x, wgate, fc1w, fc2w, x_f8, w1t8, w2t8, top_idx, gates, counts);
  hipLaunchKernelGGL(assign_kernel, dim3(Bn / 256), dim3(256), 0, stream,
                     top_idx, counts, cursors, s2r, r2s);
  hipLaunchKernelGGL((fp8_gemm_kernel<true, Hn, Dn, 1>), dim3(Hn / 64, 32, En), dim3(256),
                     0, stream, x_f8, w1t8, fc1b, counts, s2r, hbuf8,
                     (float*)nullptr, (float*)nullptr);
  hipLaunchKernelGGL((fp8_gemm_kernel<false, On, Hn, 2>), dim3((On / 64) * 2, 32, En), dim3(256),
                     0, stream, hbuf8, w2t8, fc2b, counts, s2r, (u8*)nullptr,
                     l2buf, l2buf1);
  hipLaunchKernelGGL(combine_kernel, dim3(Bn), dim3(256), 0, stream, l2buf, l2buf1, r2s, gates, out);
}

// Round 20
// 111.959 us; speedup vs baseline: 1.0327x; 1.0186x over previous
//
#include <hip/hip_runtime.h>
#include <stdint.h>

#define Bn 2048
#define Dn 1024
#define Hn 2048
#define On 512
#define En 8

typedef float f32x4 __attribute__((ext_vector_type(4)));
typedef unsigned char u8;

__device__ __forceinline__ void gload16(const void* g, void* l) {
  __builtin_amdgcn_global_load_lds((const uint32_t*)g, (uint32_t*)l, 16, 0, 0);
}

__device__ __forceinline__ u8 f2fp8(float v) {
  int w = __builtin_amdgcn_cvt_pk_fp8_f32(v, v, 0, false);
  return (u8)(w & 0xff);
}

// ---------------- init: zero counts/cursors every launch (determinism) ----------------
__global__ void init_kernel(int* counts, int* cursors) {
  int t = threadIdx.x;
  if (t < En) { counts[t] = 0; cursors[t] = 0; }
}

// == fused prep: gating+x->fp8 (no LDS) | tcast fc1_w->fp8 | tcast fc2_w->fp8 ==
#define NB_G (Bn / 8)                         // 256 blocks x 8 rows
#define NB_T1 ((Dn / 256) * (Hn / 64) * En)   // 4*32*8 = 1024
#define NB_T2 ((Hn / 256) * (On / 64) * En)   // 8*8*8  = 512
#define WSCALE 64.0f

// 256(r) x 64(c) transpose tile -> fp8 (x WSCALE).
// LDS: column-major dwords, column stride 65 dw -> write bank = (4k+rg) mod 32 (2-way),
// read bank = (c+16q+i) mod 32 (2-way). Output: 256 B contiguous per output row.
__device__ __forceinline__ void tcast_f8_256(const float* __restrict__ inp,
                                             u8* __restrict__ outp,
                                             int R, int C, int r0, int c0, uint32_t* L) {
  int t = threadIdx.x;
  int cc4 = (t & 15) * 4;   // col base 0..60
  int rg = t >> 4;          // 0..15
#pragma unroll
  for (int p = 0; p < 4; p++) {
    int rbase = p * 64 + rg * 4;
    uint32_t wds[4] = {0, 0, 0, 0};
#pragma unroll
    for (int i = 0; i < 4; i++) {
      float4 v = *(const float4*)&inp[(size_t)(r0 + rbase + i) * C + c0 + cc4];
      wds[0] |= (uint32_t)f2fp8(v.x * WSCALE) << (8 * i);
      wds[1] |= (uint32_t)f2fp8(v.y * WSCALE) << (8 * i);
      wds[2] |= (uint32_t)f2fp8(v.z * WSCALE) << (8 * i);
      wds[3] |= (uint32_t)f2fp8(v.w * WSCALE) << (8 * i);
    }
    int rd = p * 16 + rg;
#pragma unroll
    for (int j = 0; j < 4; j++) L[(cc4 + j) * 65 + rd] = wds[j];
  }
  __syncthreads();
  int c = t >> 2, q = t & 3;  // output row c (0..63), 64B chunk q
  uint32_t dw[16];
#pragma unroll
  for (int i = 0; i < 16; i++) dw[i] = L[c * 65 + q * 16 + i];
  u8* op = &outp[(size_t)(c0 + c) * R + r0 + q * 64];
#pragma unroll
  for (int s = 0; s < 4; s++) {
    int4 o = make_int4((int)dw[4 * s], (int)dw[4 * s + 1], (int)dw[4 * s + 2],
                       (int)dw[4 * s + 3]);
    *(int4*)(op + 16 * s) = o;
  }
}

__global__ __launch_bounds__(256) void prep_kernel(
    const float* __restrict__ x, const float* __restrict__ wg,
    const float* __restrict__ fc1w, const float* __restrict__ fc2w,
    u8* __restrict__ x_f8, u8* __restrict__ w1t8, u8* __restrict__ w2t8,
    int* __restrict__ top_idx, float* __restrict__ gates, int* __restrict__ counts) {
  __shared__ __align__(16) uint32_t smem[64 * 65];  // 16.3 KB transpose tile
  __shared__ int lcnt[En];
  int bid = blockIdx.x;
  int t = threadIdx.x;

  if (bid < NB_G) {
    // ---- gating + x->fp8: 8 rows/block, no LDS (wg read direct, L1-resident) ----
    if (t < En) lcnt[t] = 0;
    __syncthreads();
    int w = t >> 6, lane = t & 63;
#pragma unroll
    for (int r = 0; r < 2; r++) {
      int b = bid * 8 + w * 2 + r;
      const float* xr = x + (size_t)b * Dn;
      u8* xo = x_f8 + (size_t)b * Dn;
      float acc[En];
#pragma unroll
      for (int e = 0; e < En; e++) acc[e] = 0.f;
#pragma unroll
      for (int j = 0; j < 16; j++) {
        int d = lane + j * 64;
        float xv = xr[d];
        xo[d] = f2fp8(xv);
        float4 wa = *(const float4*)(wg + (size_t)d * En);
        float4 wb = *(const float4*)(wg + (size_t)d * En + 4);
        acc[0] += xv * wa.x; acc[1] += xv * wa.y;
        acc[2] += xv * wa.z; acc[3] += xv * wa.w;
        acc[4] += xv * wb.x; acc[5] += xv * wb.y;
        acc[6] += xv * wb.z; acc[7] += xv * wb.w;
      }
#pragma unroll
      for (int off = 32; off; off >>= 1) {
#pragma unroll
        for (int e = 0; e < En; e++) acc[e] += __shfl_down(acc[e], off);
      }
      if (lane == 0) {
        float best = -1e30f, second = -1e30f; int bi = 0, si = 0;
#pragma unroll
        for (int e = 0; e < En; e++) {
          float l = acc[e];
          if (l > best) { second = best; si = bi; best = l; bi = e; }
          else if (l > second) { second = l; si = e; }
        }
        float e1 = expf(second - best);
        float inv = 1.f / (1.f + e1);
        top_idx[2 * b] = bi; top_idx[2 * b + 1] = si;
        gates[2 * b] = inv;  gates[2 * b + 1] = e1 * inv;
        atomicAdd(&lcnt[bi], 1);
        atomicAdd(&lcnt[si], 1);
      }
    }
    __syncthreads();
    if (t < En) {
      int c = lcnt[t];
      if (c) atomicAdd(&counts[t], c);
    }
  } else if (bid < NB_G + NB_T1) {
    // ---- fc1_w [E][Dn][Hn] -> w1t8 [E][Hn][Dn] fp8 ----
    int idx = bid - NB_G;
    constexpr int TPE = (Dn / 256) * (Hn / 64);
    int z = idx / TPE, rem = idx % TPE;
    int r0 = (rem / (Hn / 64)) * 256, c0 = (rem % (Hn / 64)) * 64;
    tcast_f8_256(fc1w + (size_t)z * Dn * Hn, w1t8 + (size_t)z * Dn * Hn, Dn, Hn, r0, c0, smem);
  } else {
    // ---- fc2_w [E][Hn][On] -> w2t8 [E][On][Hn] fp8 ----
    int idx = bid - NB_G - NB_T1;
    constexpr int TPE = (Hn / 256) * (On / 64);
    int z = idx / TPE, rem = idx % TPE;
    int r0 = (rem / (On / 64)) * 256, c0 = (rem % (On / 64)) * 64;
    tcast_f8_256(fc2w + (size_t)z * Hn * On, w2t8 + (size_t)z * Hn * On, Hn, On, r0, c0, smem);
  }
}

// -------- assign rows to compact slots (offsets computed inline from counts) --------
__global__ void assign_kernel(const int* __restrict__ top_idx, const int* __restrict__ counts,
                              int* cursors, int* __restrict__ s2r, int* __restrict__ r2s) {
  int b = blockIdx.x * 256 + threadIdx.x;
  if (b >= Bn) return;
  int offs[En];
  int s = 0;
#pragma unroll
  for (int e = 0; e < En; e++) { offs[e] = s; s += counts[e]; }
#pragma unroll
  for (int k = 0; k < 2; k++) {
    int e = top_idx[2 * b + k];
    int pos = atomicAdd(&cursors[e], 1);
    int slot = offs[e] + pos;
    s2r[slot] = b;
    r2s[2 * b + k] = slot;
  }
}

// ---- fp8 grouped GEMM: 64x64 x 64B-K-step, 4 waves (2Mx2N), mfma_f32_16x16x32_fp8_fp8 ----
// r16/r17-proven structure. W pre-scaled x64 -> epilogue unscales 1/64 before bias.
template <bool FC1, int N, int K, int SPLITK>
__global__ __launch_bounds__(256, 8) void fp8_gemm_kernel(
    const u8* __restrict__ A, const u8* __restrict__ WT,
    const float* __restrict__ bias, const int* __restrict__ counts,
    const int* __restrict__ s2r,
    u8* __restrict__ outH8, float* __restrict__ outL, float* __restrict__ outL2) {
  constexpr int NBL = N / 64;
  constexpr int KS = K / SPLITK;
  constexpr int NT = KS / 64;
  int e = blockIdx.z;
  int cnt = counts[e];
  int rb = blockIdx.y;
  if (rb * 64 >= cnt) return;
  int base = 0;
#pragma unroll
  for (int i = 0; i < En; i++) base += (i < e) ? counts[i] : 0;
  int ks = blockIdx.x / NBL;
  int nb = (blockIdx.x % NBL) * 64;
  int k0 = ks * KS;
  __shared__ __align__(16) u8 As[64 * 64];  // 4 KB
  __shared__ __align__(16) u8 Bs[64 * 64];  // 4 KB
  int t = threadIdx.x;
  int lane = t & 63, w = t >> 6;
  int wr = w >> 1, wc = w & 1;

  int srow = t >> 2;                           // 0..63 staging row
  int sslot = (t & 3) ^ ((srow >> 1) & 3);     // pre-swizzled global 16B slot
  int scol = sslot * 16;

  int lr = rb * 64 + srow;
  int lrc = lr < cnt ? lr : cnt - 1;
  const u8* aptr = A + (size_t)(FC1 ? s2r[base + lrc] : (base + lrc)) * K + k0 + scol;
  const u8* bptr = WT + ((size_t)e * N + nb + srow) * K + k0 + scol;

  f32x4 zero = {0.f, 0.f, 0.f, 0.f};
  f32x4 acc[2][2];
#pragma unroll
  for (int m = 0; m < 2; m++)
#pragma unroll
    for (int n = 0; n < 2; n++) acc[m][n] = zero;

  int a_r = wr * 32 + (lane & 15);       // A fragment row
  int b_r = wc * 32 + (lane & 15);       // B fragment row
  int rkey = ((lane & 15) >> 1) & 3;     // (row>>1)&3 (row bases mult of 16 -> invariant)
  int slb = (lane >> 4) >> 1;            // logical 16B-slot sub-index (0/1)
  int half = ((lane >> 4) & 1) * 8;      // 8B half within slot

  for (int kt = 0; kt < NT; kt++) {
    gload16(aptr + kt * 64, &As[t * 16]);   // linear dest: row t>>2, slot t&3
    gload16(bptr + kt * 64, &Bs[t * 16]);
    __syncthreads();  // drains vmcnt before LDS reads
#pragma unroll
    for (int kk = 0; kk < 2; kk++) {
      long af[2], bfr[2];
#pragma unroll
      for (int m = 0; m < 2; m++)
        af[m] = *(const long*)(As + (a_r + m * 16) * 64 +
                               (((kk * 2 + slb) ^ rkey) << 4) + half);
#pragma unroll
      for (int n = 0; n < 2; n++)
        bfr[n] = *(const long*)(Bs + (b_r + n * 16) * 64 +
                                (((kk * 2 + slb) ^ rkey) << 4) + half);
#pragma unroll
      for (int m = 0; m < 2; m++)
#pragma unroll
        for (int n = 0; n < 2; n++)
          acc[m][n] = __builtin_amdgcn_mfma_f32_16x16x32_fp8_fp8(af[m], bfr[n], acc[m][n], 0, 0, 0);
    }
    __syncthreads();  // protect LDS before next stage
  }

  // epilogue: D layout col=lane&15, row=(lane>>4)*4+i; unscale 1/64
  const float INV = 1.0f / WSCALE;
  float* dst = (SPLITK > 1 && ks > 0) ? outL2 : outL;
  int lr0 = rb * 64 + wr * 32;
#pragma unroll
  for (int m = 0; m < 2; m++) {
#pragma unroll
    for (int i = 0; i < 4; i++) {
      int orow = lr0 + m * 16 + (lane >> 4) * 4 + i;
      if (orow < cnt) {
        int slot = base + orow;
#pragma unroll
        for (int n = 0; n < 2; n++) {
          int col = nb + wc * 32 + n * 16 + (lane & 15);
          if (FC1) {
            float v = acc[m][n][i] * INV + bias[e * N + col];
            float g = 0.5f * v * (1.0f + erff(v * 0.70710678118654752f));
            outH8[(size_t)slot * N + col] = f2fp8(g);
          } else {
            float v = acc[m][n][i] * INV + (ks == 0 ? bias[e * N + col] : 0.f);
            dst[(size_t)slot * N + col] = v;
          }
        }
      }
    }
  }
}

// ---------------- combine: sum 2 split-K partials, logsoftmax over O=512, weighted sum ----------------
__device__ __forceinline__ float blk_reduce(float v, bool ismax) {
  __shared__ float sbuf[4];
  int lane = threadIdx.x & 63, w = threadIdx.x >> 6;
#pragma unroll
  for (int off = 32; off; off >>= 1) {
    float o = __shfl_down(v, off);
    v = ismax ? fmaxf(v, o) : (v + o);
  }
  __syncthreads();
  if (lane == 0) sbuf[w] = v;
  __syncthreads();
  float r = sbuf[0];
#pragma unroll
  for (int i = 1; i < 4; i++) r = ismax ? fmaxf(r, sbuf[i]) : (r + sbuf[i]);
  return r;
}

__global__ void combine_kernel(const float* __restrict__ l2a, const float* __restrict__ l2b,
                               const int* __restrict__ r2s, const float* __restrict__ gates,
                               float* __restrict__ out) {
  int b = blockIdx.x, t = threadIdx.x;
  float c0 = 0.f, c1 = 0.f;
#pragma unroll
  for (int k = 0; k < 2; k++) {
    int slot = r2s[2 * b + k];
    float g = gates[2 * b + k];
    const float* lp0 = l2a + (size_t)slot * On;
    const float* lp1 = l2b + (size_t)slot * On;
    float v0 = lp0[t] + lp1[t];
    float v1 = lp0[t + 256] + lp1[t + 256];
    float m = blk_reduce(fmaxf(v0, v1), true);
    float s = blk_reduce(expf(v0 - m) + expf(v1 - m), false);
    float lse = m + logf(s);
    c0 += g * expf(v0 - lse);
    c1 += g * expf(v1 - lse);
  }
  const float EPSv = 2.220446049250313e-16f;
  out[(size_t)b * On + t] = logf(fmaxf(c0, EPSv));
  out[(size_t)b * On + t + 256] = logf(fmaxf(c1, EPSv));
}

extern "C" void kernel_launch(void* const* d_in, const int* in_sizes, int n_in,
                              void* d_out, int out_size, void* d_ws, size_t ws_size,
                              hipStream_t stream) {
  const float* x = (const float*)d_in[0];
  const float* wgate = (const float*)d_in[1];
  const float* fc1w = (const float*)d_in[2];
  const float* fc1b = (const float*)d_in[3];
  const float* fc2w = (const float*)d_in[4];
  const float* fc2b = (const float*)d_in[5];
  float* out = (float*)d_out;

  char* ws = (char*)d_ws;
  size_t o = 0;
  u8* x_f8     = (u8*)(ws + o);    o += (size_t)Bn * Dn;          // 2 MB
  u8* w1t8     = (u8*)(ws + o);    o += (size_t)En * Hn * Dn;     // 16 MB [E][H][D] fp8
  u8* w2t8     = (u8*)(ws + o);    o += (size_t)En * On * Hn;     // 8 MB  [E][O][H] fp8
  u8* hbuf8    = (u8*)(ws + o);    o += (size_t)2 * Bn * Hn;      // 4 MB  [slot][H] fp8
  float* l2buf = (float*)(ws + o); o += (size_t)2 * Bn * On * 4;  // 8 MB partial 0
  int* top_idx = (int*)(ws + o);   o += (size_t)Bn * 2 * 4;
  float* gates = (float*)(ws + o); o += (size_t)Bn * 2 * 4;
  int* r2s     = (int*)(ws + o);   o += (size_t)Bn * 2 * 4;
  int* s2r     = (int*)(ws + o);   o += (size_t)2 * Bn * 4;
  int* counts  = (int*)(ws + o);   o += 64;
  int* cursors = (int*)(ws + o);   o += 64;
  // split-K partial 1 (8 MB) aliases w1t8 (16 MB): w1t8 is fully consumed by fc1
  // (completes before fc2 starts, same stream) and rewritten by prep each launch.
  float* l2buf1 = (float*)w1t8;

  hipLaunchKernelGGL(init_kernel, dim3(1), dim3(64), 0, stream, counts, cursors);
  hipLaunchKernelGGL(prep_kernel, dim3(NB_G + NB_T1 + NB_T2), dim3(256), 0, stream,
                     x, wgate, fc1w, fc2w, x_f8, w1t8, w2t8, top_idx, gates, counts);
  hipLaunchKernelGGL(assign_kernel, dim3(Bn / 256), dim3(256), 0, stream,
                     top_idx, counts, cursors, s2r, r2s);
  hipLaunchKernelGGL((fp8_gemm_kernel<true, Hn, Dn, 1>), dim3(Hn / 64, 32, En), dim3(256),
                     0, stream, x_f8, w1t8, fc1b, counts, s2r, hbuf8,
                     (float*)nullptr, (float*)nullptr);
  hipLaunchKernelGGL((fp8_gemm_kernel<false, On, Hn, 2>), dim3((On / 64) * 2, 32, En), dim3(256),
                     0, stream, hbuf8, w2t8, fc2b, counts, s2r, (u8*)nullptr,
                     l2buf, l2buf1);
  hipLaunchKernelGGL(combine_kernel, dim3(Bn), dim3(256), 0, stream, l2buf, l2buf1, r2s, gates, out);
}